// Round 1
// baseline (23594.258 us; speedup 1.0000x reference)
//
#include <hip/hip_runtime.h>

#define KUc 512
#define Hc 90
#define H3c 270
#define Bc 32
#define Tc 64
#define ROWSc 64
#define BLKT 512

__device__ __forceinline__ float sigf(float x) { return 1.0f / (1.0f + __expf(-x)); }
__device__ __forceinline__ float tanhfast(float x) {
    float e = __expf(2.0f * x);
    return 1.0f - 2.0f / (e + 1.0f);
}

// Precompute: ce_sync[k][m] = concept_emb[k] @ W_sync[2H:3H] + b_sync   (time-invariant)
//             gi0[c] = relu(b_agg) @ Wi_rnn + bi_rnn                    (inactive-row GRU input gates)
__global__ void skt_prep(const float* __restrict__ concept_emb, const float* __restrict__ W_sync,
                         const float* __restrict__ b_sync, const float* __restrict__ b_agg,
                         const float* __restrict__ Wi_rnn, const float* __restrict__ bi_rnn,
                         float* __restrict__ ce_sync, float* __restrict__ gi0) {
    int k = blockIdx.x;
    int m = threadIdx.x;
    if (m < Hc) {
        float acc = b_sync[m];
        for (int kk = 0; kk < Hc; ++kk)
            acc += concept_emb[k * Hc + kk] * W_sync[(2 * Hc + kk) * Hc + m];
        ce_sync[k * Hc + m] = acc;
    }
    if (k == 0) {
        __shared__ float inf0[Hc];
        if (m < Hc) inf0[m] = fmaxf(b_agg[m], 0.0f);
        __syncthreads();
        for (int c = m; c < H3c; c += blockDim.x) {
            float acc = bi_rnn[c];
            for (int kk = 0; kk < Hc; ++kk) acc += inf0[kk] * Wi_rnn[kk * H3c + c];
            gi0[c] = acc;
        }
    }
}

// One timestep. Grid: 256 blocks = 32 batches x 8 row-tiles of 64 rows. Block: 512 threads.
__global__ __launch_bounds__(BLKT, 1)
void skt_step(const int* __restrict__ qs, const int* __restrict__ as_,
              const float* __restrict__ response_emb, const float* __restrict__ concept_emb,
              const float* __restrict__ nb_adj, const float* __restrict__ succ_adj,
              const float* __restrict__ Wi_self, const float* __restrict__ Wh_self,
              const float* __restrict__ bi_self, const float* __restrict__ bh_self,
              const float* __restrict__ Wi_rnn, const float* __restrict__ Wh_rnn,
              const float* __restrict__ bi_rnn, const float* __restrict__ bh_rnn,
              const float* __restrict__ W_sync, const float* __restrict__ W_prop,
              const float* __restrict__ b_prop, const float* __restrict__ W_agg,
              const float* __restrict__ b_agg, const float* __restrict__ W_out,
              const float* __restrict__ b_out, const float* __restrict__ ce_sync,
              const float* __restrict__ gi0, const float* __restrict__ st_in,
              float* __restrict__ st_out, float* __restrict__ out, int t) {
    // whgh: first holds Wh_rnn staged as [90][288] (cols 270..287 zero); after the matmul
    // barrier it is reused as gh/new-state storage [64][272].
    __shared__ alignas(16) float whgh[Hc * 288];
    __shared__ float h_s[ROWSc * Hc];
    __shared__ float re_s[Hc], ss_s[Hc], ns_s[Hc], nsync_s[Hc], pvec_s[Hc], reflec_s[Hc];
    __shared__ float act_s[Hc], inf_s[Hc], stnb_s[Hc], wout_s[Hc];
    __shared__ float giself_s[H3c], ghself_s[H3c], gi0_s[H3c], bh_s[H3c], gir_s[H3c];
    __shared__ float nbv_s[ROWSc], succv_s[ROWSc];
    __shared__ int active_s[ROWSc];

    const int tid = threadIdx.x;
    const int b = blockIdx.x >> 3;
    const int k0 = (blockIdx.x & 7) * ROWSc;
    const int q = qs[b * Tc + t];
    const int a = as_[b * Tc + t];

    // ---------------- stage ----------------
    for (int i = tid; i < Hc * 288; i += BLKT) {
        int kk = i / 288, c = i - kk * 288;
        whgh[i] = (c < H3c) ? Wh_rnn[kk * H3c + c] : 0.0f;
    }
    for (int i = tid; i < ROWSc * Hc; i += BLKT)
        h_s[i] = st_in[(size_t)(b * KUc + k0) * Hc + i];
    for (int c = tid; c < H3c; c += BLKT) { bh_s[c] = bh_rnn[c]; gi0_s[c] = gi0[c]; }
    if (tid < Hc) {
        re_s[tid] = response_emb[(size_t)a * Hc + tid];
        ss_s[tid] = st_in[(size_t)(b * KUc + q) * Hc + tid];
        wout_s[tid] = W_out[tid];
        reflec_s[tid] = 0.0f;
    }
    if (tid < ROWSc) {
        int k = k0 + tid;
        float nv = nb_adj[(size_t)q * KUc + k];
        float sv = succ_adj[(size_t)q * KUc + k];
        nbv_s[tid] = nv; succv_s[tid] = sv;
        active_s[tid] = (nv != 0.0f || sv != 0.0f || k == q) ? 1 : 0;
    }
    __syncthreads();

    // ---------------- phase 0: self GRU, nsync, pvec (redundant per block; tiny) ----------
    for (int c = tid; c < H3c; c += BLKT) {
        float ai = bi_self[c], ah = bh_self[c];
        for (int kk = 0; kk < Hc; ++kk) {
            ai += re_s[kk] * Wi_self[kk * H3c + c];
            ah += ss_s[kk] * Wh_self[kk * H3c + c];
        }
        giself_s[c] = ai; ghself_s[c] = ah;
    }
    __syncthreads();
    if (tid < Hc) {
        float r = sigf(giself_s[tid] + ghself_s[tid]);
        float z = sigf(giself_s[Hc + tid] + ghself_s[Hc + tid]);
        float g = tanhfast(giself_s[2 * Hc + tid] + r * ghself_s[2 * Hc + tid]);
        ns_s[tid] = (1.0f - z) * g + z * ss_s[tid];
    }
    __syncthreads();
    if (tid < Hc) {
        float an = 0.0f, ap = b_prop[tid];
        for (int kk = 0; kk < Hc; ++kk) an += ns_s[kk] * W_sync[(Hc + kk) * Hc + tid];
        nsync_s[tid] = an;
        for (int kk = 0; kk < Hc; ++kk) ap += (ns_s[kk] - ss_s[kk]) * W_prop[kk * Hc + tid];
        for (int kk = 0; kk < Hc; ++kk)
            ap += concept_emb[(size_t)q * Hc + kk] * W_prop[(Hc + kk) * Hc + tid];
        pvec_s[tid] = fmaxf(ap, 0.0f);
    }
    __syncthreads();

    // ---------------- reflec: only the block owning the self row computes it --------------
    if (q >= k0 && q < k0 + ROWSc) {
        for (int kp = 0; kp < KUc; ++kp) {
            float nv = nb_adj[(size_t)q * KUc + kp];
            if (nv != 0.0f) {               // block-uniform
                if (tid < Hc) stnb_s[tid] = st_in[(size_t)(b * KUc + kp) * Hc + tid];
                __syncthreads();
                if (tid < Hc) {
                    float acc = nsync_s[tid] + ce_sync[kp * Hc + tid];
                    for (int kk = 0; kk < Hc; ++kk) acc += stnb_s[kk] * W_sync[kk * Hc + tid];
                    reflec_s[tid] += nv * fmaxf(acc, 0.0f);
                }
                __syncthreads();
            }
        }
    }
    __syncthreads();

    // ---------------- gh = states @ Wh_rnn + bh (the per-step floor) ----------------------
    const int tr = tid >> 5;   // 0..15, 4 rows each
    const int tc = tid & 31;   // col groups: [tc*4..+3], [128+tc*4..+3], [256+tc]
    const int r0 = tr * 4;
    float acc[4][9];
#pragma unroll
    for (int rr = 0; rr < 4; ++rr)
#pragma unroll
        for (int j = 0; j < 9; ++j) acc[rr][j] = 0.0f;

    for (int kk = 0; kk < Hc; ++kk) {
        const float4 w0 = *(const float4*)&whgh[kk * 288 + tc * 4];
        const float4 w1 = *(const float4*)&whgh[kk * 288 + 128 + tc * 4];
        const float w2 = whgh[kk * 288 + 256 + tc];
#pragma unroll
        for (int rr = 0; rr < 4; ++rr) {
            float hv = h_s[(r0 + rr) * Hc + kk];
            acc[rr][0] += hv * w0.x; acc[rr][1] += hv * w0.y;
            acc[rr][2] += hv * w0.z; acc[rr][3] += hv * w0.w;
            acc[rr][4] += hv * w1.x; acc[rr][5] += hv * w1.y;
            acc[rr][6] += hv * w1.z; acc[rr][7] += hv * w1.w;
            acc[rr][8] += hv * w2;
        }
    }
    __syncthreads();   // all Wh reads done; whgh becomes gh[64][272]
#pragma unroll
    for (int rr = 0; rr < 4; ++rr) {
        int r = r0 + rr;
#pragma unroll
        for (int j = 0; j < 4; ++j) {
            int c = tc * 4 + j;
            whgh[r * 272 + c] = acc[rr][j] + bh_s[c];
        }
#pragma unroll
        for (int j = 0; j < 4; ++j) {
            int c = 128 + tc * 4 + j;
            whgh[r * 272 + c] = acc[rr][4 + j] + bh_s[c];
        }
        int c2 = 256 + tc;
        if (c2 < H3c) whgh[r * 272 + c2] = acc[rr][8] + bh_s[c2];
    }
    __syncthreads();

    // ---------------- active rows: sync/prop -> agg -> gi -> GRU (sparse, ~4%) ------------
    for (int ar = 0; ar < ROWSc; ++ar) {
        if (!active_s[ar]) continue;       // block-uniform
        const int k = k0 + ar;
        if (tid < Hc) {
            float sy = 0.0f;
            float nv = nbv_s[ar];
            if (nv != 0.0f) {
                float accs = nsync_s[tid] + ce_sync[k * Hc + tid];
                for (int kk = 0; kk < Hc; ++kk) accs += h_s[ar * Hc + kk] * W_sync[kk * Hc + tid];
                sy = nv * fmaxf(accs, 0.0f);
            }
            if (k == q) sy += reflec_s[tid];
            act_s[tid] = 0.5f * sy + 0.5f * succv_s[ar] * pvec_s[tid];
        }
        __syncthreads();
        if (tid < Hc) {
            float accg = b_agg[tid];
            for (int kk = 0; kk < Hc; ++kk) accg += act_s[kk] * W_agg[kk * Hc + tid];
            inf_s[tid] = fmaxf(accg, 0.0f);
        }
        __syncthreads();
        for (int c = tid; c < H3c; c += BLKT) {
            float accg = bi_rnn[c];
            for (int kk = 0; kk < Hc; ++kk) accg += inf_s[kk] * Wi_rnn[kk * H3c + c];
            gir_s[c] = accg;
        }
        __syncthreads();
        if (tid < Hc) {
            float r = sigf(gir_s[tid] + whgh[ar * 272 + tid]);
            float z = sigf(gir_s[Hc + tid] + whgh[ar * 272 + Hc + tid]);
            float g = tanhfast(gir_s[2 * Hc + tid] + r * whgh[ar * 272 + 2 * Hc + tid]);
            whgh[ar * 272 + tid] = (1.0f - z) * g + z * h_s[ar * Hc + tid];
        }
        __syncthreads();
    }

    // ---------------- inactive rows: GRU with constant input gates gi0 --------------------
    for (int i = tid; i < ROWSc * Hc; i += BLKT) {
        int r = i / Hc, m = i - r * Hc;
        if (active_s[r]) continue;
        float rg = sigf(gi0_s[m] + whgh[r * 272 + m]);
        float z = sigf(gi0_s[Hc + m] + whgh[r * 272 + Hc + m]);
        float g = tanhfast(gi0_s[2 * Hc + m] + rg * whgh[r * 272 + 2 * Hc + m]);
        whgh[r * 272 + m] = (1.0f - z) * g + z * h_s[i];
    }
    __syncthreads();

    // ---------------- out = sigmoid(ns @ W_out + b_out); store new states -----------------
    if (tid < ROWSc) {
        float accp = b_out[0];
        for (int m = 0; m < Hc; ++m) accp += whgh[tid * 272 + m] * wout_s[m];
        out[(size_t)t * Bc * KUc + (size_t)b * KUc + k0 + tid] = sigf(accp);
    }
    for (int i = tid; i < ROWSc * Hc; i += BLKT) {
        int r = i / Hc, m = i - r * Hc;
        st_out[(size_t)(b * KUc + k0) * Hc + i] = whgh[r * 272 + m];
    }
}

extern "C" void kernel_launch(void* const* d_in, const int* in_sizes, int n_in,
                              void* d_out, int out_size, void* d_ws, size_t ws_size,
                              hipStream_t stream) {
    const int* questions = (const int*)d_in[0];
    const int* answers = (const int*)d_in[1];
    const float* response_emb = (const float*)d_in[2];
    const float* concept_emb = (const float*)d_in[3];
    const float* nb_adj = (const float*)d_in[4];
    const float* succ_adj = (const float*)d_in[5];
    const float* Wi_self = (const float*)d_in[6];
    const float* Wh_self = (const float*)d_in[7];
    const float* bi_self = (const float*)d_in[8];
    const float* bh_self = (const float*)d_in[9];
    const float* Wi_rnn = (const float*)d_in[10];
    const float* Wh_rnn = (const float*)d_in[11];
    const float* bi_rnn = (const float*)d_in[12];
    const float* bh_rnn = (const float*)d_in[13];
    const float* W_sync = (const float*)d_in[14];
    const float* b_sync = (const float*)d_in[15];
    const float* W_prop = (const float*)d_in[16];
    const float* b_prop = (const float*)d_in[17];
    const float* W_agg = (const float*)d_in[18];
    const float* b_agg = (const float*)d_in[19];
    const float* W_out = (const float*)d_in[20];
    const float* b_out = (const float*)d_in[21];

    float* out = (float*)d_out;
    float* stA = out + (size_t)Tc * Bc * KUc;   // final-states region of d_out = ping buffer
    float* ce_sync = (float*)d_ws;
    float* gi0 = ce_sync + KUc * Hc;
    float* stB = gi0 + 512;                     // pong buffer in workspace

    hipMemsetAsync(stA, 0, (size_t)Bc * KUc * Hc * sizeof(float), stream);
    skt_prep<<<KUc, 128, 0, stream>>>(concept_emb, W_sync, b_sync, b_agg, Wi_rnn, bi_rnn,
                                      ce_sync, gi0);
    for (int t = 0; t < Tc; ++t) {
        const float* sin = (t & 1) ? stB : stA;
        float* sout = (t & 1) ? stA : stB;
        skt_step<<<Bc * 8, BLKT, 0, stream>>>(
            questions, answers, response_emb, concept_emb, nb_adj, succ_adj,
            Wi_self, Wh_self, bi_self, bh_self, Wi_rnn, Wh_rnn, bi_rnn, bh_rnn,
            W_sync, W_prop, b_prop, W_agg, b_agg, W_out, b_out,
            ce_sync, gi0, sin, sout, out, t);
    }
}